// Round 1
// 126.878 us; speedup vs baseline: 1.0316x; 1.0316x over previous
//
#include <hip/hip_runtime.h>
#include <math.h>

// Disable FP contraction globally: selection thresholds (iou >= 0.5) must be
// bit-exact vs the numpy float32 reference; FMA rewrites would perturb them.
#pragma clang fp contract(off)

#define BN    16      // batch
#define NP    2000    // proposals per batch
#define NG    200     // gt boxes per batch
#define NT    200     // output slots (T)
#define PMAX  66      // int(T * 0.33)
#define EPSF  1e-6f
#define MH    28
#define MW    28
#define HM    56      // input mask H=W
#define NPIX  (HM*HM) // 3136
#define NSLOT 128     // staged slots per batch (pos_count <= 66)
#define NW    49      // 64-bit words per bit-packed 56x56 plane (3136/64)

// ---------------------------------------------------------------------------
// Kernel A: per-proposal reductions over GTs.
// grid (ceil(NP/256), BN), block 256.
// ---------------------------------------------------------------------------
__global__ __launch_bounds__(256) void kA(
    const float* __restrict__ proposals, const int* __restrict__ cls_ids,
    const float* __restrict__ boxes,
    int* __restrict__ flag_ws, int* __restrict__ assign_ws)
{
#pragma clang fp contract(off)
  const int b = blockIdx.y;
  __shared__ float4 gbox[NG];
  __shared__ float  garea[NG];
  __shared__ int    gflag[NG];   // 1 non-crowd, 2 crowd, 0 neither

  for (int j = threadIdx.x; j < NG; j += 256) {
    float4 g = reinterpret_cast<const float4*>(boxes + (size_t)b * NG * 4)[j];
    int c = cls_ids[b * NG + j];
    bool vg = (g.x != 0.f) || (g.y != 0.f) || (g.z != 0.f) || (g.w != 0.f);
    gbox[j]  = g;
    garea[j] = (g.z - g.x) * (g.w - g.y);
    gflag[j] = vg ? (c > 0 ? 1 : (c < 0 ? 2 : 0)) : 0;
  }
  __syncthreads();

  int i = blockIdx.x * 256 + threadIdx.x;
  if (i >= NP) return;

  float4 p = reinterpret_cast<const float4*>(proposals + (size_t)b * NP * 4)[i];
  bool vp = (p.x != 0.f) || (p.y != 0.f) || (p.z != 0.f) || (p.w != 0.f);
  float pa = (p.z - p.x) * (p.w - p.y);

  float best = -3.0e38f;   // first iteration always wins -> argmax-first
  int   bestj = 0;
  float cmax = 0.f;
  for (int j = 0; j < NG; ++j) {
    float4 g = gbox[j];
    float iy = fmaxf(fminf(p.z, g.z) - fmaxf(p.x, g.x), 0.f);
    float ix = fmaxf(fminf(p.w, g.w) - fmaxf(p.y, g.y), 0.f);
    float inter = iy * ix;
    float uni = (pa + garea[j]) - inter;
    float iou = inter / fmaxf(uni, EPSF);
    int fl = gflag[j];
    float v = (fl == 1) ? iou : -1.0f;           // ov_nc
    if (v > best) { best = v; bestj = j; }       // strict > => first max
    if (fl == 2) cmax = fmaxf(cmax, iou);
  }
  bool pos = vp && (best >= 0.5f);
  bool neg = vp && (best < 0.5f) && (cmax < 0.001f);
  flag_ws[b * NP + i]   = pos ? 1 : (neg ? 2 : 0);
  assign_ws[b * NP + i] = bestj;
}

// ---------------------------------------------------------------------------
// Kernel B: stable compaction + slot assembly. grid BN, block 256.
// ---------------------------------------------------------------------------
__global__ __launch_bounds__(256) void kB(
    const float* __restrict__ proposals, const int* __restrict__ cls_ids,
    const float* __restrict__ boxes, const int* __restrict__ flag_ws,
    const int* __restrict__ assign_ws, float* __restrict__ out,
    float* __restrict__ mm_ws, int* __restrict__ ma_ws)
{
#pragma clang fp contract(off)
  const int b = blockIdx.x;
  const int tid = threadIdx.x;
  const int lane = tid & 63;
  const int wv = tid >> 6;

  __shared__ unsigned short pos_list[NP];
  __shared__ unsigned short neg_list[NP];
  __shared__ int wcp[4], wcn[4];
  __shared__ int s_pt, s_nt;
  if (tid == 0) { s_pt = 0; s_nt = 0; }
  __syncthreads();

  const int* fb = flag_ws + b * NP;
  for (int base = 0; base < NP; base += 256) {
    int i = base + tid;
    int f = (i < NP) ? fb[i] : 0;
    bool isp = (f == 1), isn = (f == 2);
    unsigned long long bp = __ballot(isp);
    unsigned long long bn = __ballot(isn);
    __syncthreads();
    if (lane == 0) { wcp[wv] = __popcll(bp); wcn[wv] = __popcll(bn); }
    __syncthreads();
    int prep = __popcll(bp & ((1ull << lane) - 1ull));
    int pren = __popcll(bn & ((1ull << lane) - 1ull));
    int bpp = 0, bnn = 0, tp = 0, tn = 0;
    for (int w = 0; w < 4; ++w) {
      if (w < wv) { bpp += wcp[w]; bnn += wcn[w]; }
      tp += wcp[w]; tn += wcn[w];
    }
    int pt = s_pt, nt = s_nt;
    if (isp) pos_list[pt + bpp + prep] = (unsigned short)i;
    if (isn) neg_list[nt + bnn + pren] = (unsigned short)i;
    __syncthreads();
    if (tid == 0) { s_pt = pt + tp; s_nt = nt + tn; }
  }
  __syncthreads();

  int pos_total = s_pt, neg_total = s_nt;
  int pos_count = min(pos_total, PMAX);
  int neg_needed = (int)floorf((float)pos_count / 0.33f) - pos_count;
  int neg_count = min(min(neg_needed, neg_total), NT - pos_count);

  if (tid < NT) {
    bool ispos = tid < pos_count;
    bool isneg = (!ispos) && (tid < pos_count + neg_count);
    float r0 = 0.f, r1 = 0.f, r2 = 0.f, r3 = 0.f;
    float d0 = 0.f, d1 = 0.f, d2 = 0.f, d3 = 0.f;
    float m0 = 0.f, m1 = 0.f, m2 = 0.f, m3 = 0.f;
    float clsf = 0.f;
    int ma = -1;
    if (ispos || isneg) {
      int i = ispos ? (int)pos_list[tid] : (int)neg_list[tid - pos_count];
      float4 p = reinterpret_cast<const float4*>(proposals + (size_t)b * NP * 4)[i];
      r0 = p.x; r1 = p.y; r2 = p.z; r3 = p.w;
      if (ispos) {
        int a = assign_ws[b * NP + i];
        ma = a;
        float4 g = reinterpret_cast<const float4*>(boxes + (size_t)b * NG * 4)[a];
        float h  = fmaxf(r2 - r0, EPSF);
        float w  = fmaxf(r3 - r1, EPSF);
        float cy = r0 + 0.5f * h;
        float cx = r1 + 0.5f * w;
        float gh = fmaxf(g.z - g.x, EPSF);
        float gw = fmaxf(g.w - g.y, EPSF);
        float gcy = g.x + 0.5f * gh;
        float gcx = g.y + 0.5f * gw;
        d0 = ((gcy - cy) / h) / 0.1f;
        d1 = ((gcx - cx) / w) / 0.1f;
        d2 = logf(gh / h) / 0.2f;
        d3 = logf(gw / w) / 0.2f;
        m0 = (r0 - g.x) / gh;
        m1 = (r1 - g.y) / gw;
        m2 = (r2 - g.x) / gh;
        m3 = (r3 - g.y) / gw;
        clsf = (float)cls_ids[b * NG + a];
      }
    }
    int s = b * NT + tid;
    float* rois = out;                         // [BN*NT*4]
    float* cls  = out + BN * NT * 4;           // [BN*NT]
    float* dlt  = out + BN * NT * 4 + BN * NT; // [BN*NT*4]
    rois[s * 4 + 0] = r0; rois[s * 4 + 1] = r1;
    rois[s * 4 + 2] = r2; rois[s * 4 + 3] = r3;
    cls[s] = clsf;
    dlt[s * 4 + 0] = d0; dlt[s * 4 + 1] = d1;
    dlt[s * 4 + 2] = d2; dlt[s * 4 + 3] = d3;
    mm_ws[s * 4 + 0] = m0; mm_ws[s * 4 + 1] = m1;
    mm_ws[s * 4 + 2] = m2; mm_ws[s * 4 + 3] = m3;
    ma_ws[s] = ma;
  }
}

// ---------------------------------------------------------------------------
// Kernel G: gather-transpose assigned masks into BIT-PACKED per-slot planes.
// Mask values are exactly {0.0, 1.0} (reference builds them as bool->f32),
// so a 56x56 plane is 49 ulls (392 B) instead of 12.5 KB of floats.
// grid (NPIX/64=49, NSLOT/64=2, BN), block 256.
//   read phase : wave lanes span slots for a fixed pixel -> the 64 gathered
//                g-values live in one 800 B row (~7 lines/pixel, same as
//                before); __ballot gives a per-pixel slot-word.
//   bit transpose: tiny 512 B LDS slot-word array + a second __ballot turns
//                per-pixel slot-words into per-slot pixel-words.
//   write phase: one 8 B store per (active slot, 64-pixel word).
// Global writes drop 25.7 MB -> 0.8 MB vs the float-staged version.
// ---------------------------------------------------------------------------
__global__ __launch_bounds__(256) void kG(
    const float* __restrict__ masks, const int* __restrict__ ma_ws,
    unsigned long long* __restrict__ bits)
{
  const int b  = blockIdx.z;
  const int s0 = blockIdx.y * 64;
  const int p0 = blockIdx.x * 64;
  __shared__ unsigned long long sw[64];  // per-pixel slot-words
  __shared__ int sma[64];
  const int tid  = threadIdx.x;
  const int lane = tid & 63;
  const int wv   = tid >> 6;
  if (tid < 64) sma[tid] = ma_ws[b * NT + s0 + tid];
  __syncthreads();

  const int g = sma[lane];               // read phase: lane = slot
  const float* mbase = masks + (size_t)b * NPIX * NG;
  for (int e = 0; e < 16; ++e) {
    int pl = e * 4 + wv;                 // pixel within this 64-pixel word
    float v = 0.f;
    if (g >= 0) v = mbase[(size_t)(p0 + pl) * NG + g];
    unsigned long long word = __ballot(v != 0.f);  // bit sl = slot sl's value
    if (lane == 0) sw[pl] = word;
  }
  __syncthreads();

  // bit transpose + write: lane = pixel, each wave emits 16 slot-words
  unsigned long long w0 = sw[lane];
  for (int k = 0; k < 16; ++k) {
    int sl = wv * 16 + k;
    unsigned long long word = __ballot((int)((w0 >> sl) & 1ULL));
    if (lane == 0 && sma[sl] >= 0)
      bits[(size_t)(b * NSLOT + s0 + sl) * NW + blockIdx.x] = word;
  }
}

// ---------------------------------------------------------------------------
// Kernel C: bilinear crop-resize from bit-packed planes. grid BN*NT, block 256.
// Plane = 49 ulls in LDS; taps are bit extracts, reconstructed values are
// exactly 0.0/1.0 so the f32 arithmetic (and rintf ties) is bit-identical to
// the float-staged version. Each active thread computes 4 consecutive pixels
// (28 % 4 == 0 -> same row), stores float4.
// ---------------------------------------------------------------------------
__global__ __launch_bounds__(256) void kC(
    const unsigned long long* __restrict__ bits, const float* __restrict__ mm_ws,
    const int* __restrict__ ma_ws, float* __restrict__ out)
{
#pragma clang fp contract(off)
  const int s = blockIdx.x;                    // b*NT + t
  float4* om = reinterpret_cast<float4*>(
      out + (size_t)(BN * NT * 9) + (size_t)s * (MH * MW));
  const int q = threadIdx.x;                   // float4 index, 196 active
  const int a = ma_ws[s];                      // block-uniform
  if (a < 0) {
    if (q < (MH * MW) / 4) om[q] = make_float4(0.f, 0.f, 0.f, 0.f);
    return;
  }

  __shared__ unsigned long long pb[NW];
  const int b = s / NT;
  const int t = s - b * NT;
  if (q < NW) pb[q] = bits[(size_t)(b * NSLOT + t) * NW + q];
  __syncthreads();
  if (q >= (MH * MW) / 4) return;

  float y1 = mm_ws[s * 4 + 0], x1 = mm_ws[s * 4 + 1];
  float y2 = mm_ws[s * 4 + 2], x2 = mm_ws[s * 4 + 3];
  float sy = (y2 - y1) * 55.0f / 27.0f;        // reference order
  float sx = (x2 - x1) * 55.0f / 27.0f;

  int px0 = q * 4;
  int my  = px0 / MW;                          // same row for all 4
  float ys = y1 * 55.0f + (float)my * sy;
  float y0f = floorf(ys);
  float wy  = ys - y0f;
  int y0i = (int)fminf(fmaxf(y0f, 0.f), 55.f);
  int y1i = (int)fminf(fmaxf(y0f + 1.0f, 0.f), 55.f);
  bool oky = (ys >= 0.f) && (ys <= 55.f);
  const int r0b = y0i * HM;
  const int r1b = y1i * HM;

  float res[4];
  for (int k = 0; k < 4; ++k) {
    int mx = (px0 + k) - my * MW;
    float xs = x1 * 55.0f + (float)mx * sx;
    float x0f = floorf(xs);
    float wx  = xs - x0f;
    int x0i = (int)fminf(fmaxf(x0f, 0.f), 55.f);
    int x1i = (int)fminf(fmaxf(x0f + 1.0f, 0.f), 55.f);
    int p00 = r0b + x0i, p01 = r0b + x1i;
    int p10 = r1b + x0i, p11 = r1b + x1i;
    float v00 = (float)((pb[p00 >> 6] >> (p00 & 63)) & 1ULL);
    float v01 = (float)((pb[p01 >> 6] >> (p01 & 63)) & 1ULL);
    float v10 = (float)((pb[p10 >> 6] >> (p10 & 63)) & 1ULL);
    float v11 = (float)((pb[p11 >> 6] >> (p11 & 63)) & 1ULL);
    float val = (v00 * (1.f - wx) + v01 * wx) * (1.f - wy)
              + (v10 * (1.f - wx) + v11 * wx) * wy;
    bool ok = oky && (xs >= 0.f) && (xs <= 55.f);
    res[k] = ok ? rintf(val) : 0.f;            // rintf = ties-even = np.round
  }
  om[q] = make_float4(res[0], res[1], res[2], res[3]);
}

// ---------------------------------------------------------------------------
extern "C" void kernel_launch(void* const* d_in, const int* in_sizes, int n_in,
                              void* d_out, int out_size, void* d_ws, size_t ws_size,
                              hipStream_t stream)
{
  const float* proposals = (const float*)d_in[0];   // (16,2000,4)
  const int*   cls_ids   = (const int*)d_in[1];     // (16,200)
  const float* boxes     = (const float*)d_in[2];   // (16,200,4)
  const float* masks     = (const float*)d_in[3];   // (16,56,56,200)
  float* out = (float*)d_out;

  char* ws = (char*)d_ws;
  int*   flag_ws   = (int*)ws;    ws += (size_t)BN * NP * sizeof(int);
  int*   assign_ws = (int*)ws;    ws += (size_t)BN * NP * sizeof(int);
  float* mm_ws     = (float*)ws;  ws += (size_t)BN * NT * 4 * sizeof(float);
  int*   ma_ws     = (int*)ws;    ws += (size_t)BN * NT * sizeof(int);
  unsigned long long* bits_ws = (unsigned long long*)ws; // BN*NSLOT*49 ulls = 0.8 MB

  dim3 gA((NP + 255) / 256, BN);
  kA<<<gA, 256, 0, stream>>>(proposals, cls_ids, boxes, flag_ws, assign_ws);
  kB<<<BN, 256, 0, stream>>>(proposals, cls_ids, boxes, flag_ws, assign_ws,
                             out, mm_ws, ma_ws);
  dim3 gG(NPIX / 64, NSLOT / 64, BN);
  kG<<<gG, 256, 0, stream>>>(masks, ma_ws, bits_ws);
  kC<<<BN * NT, 256, 0, stream>>>(bits_ws, mm_ws, ma_ws, out);
}

// Round 2
// 112.295 us; speedup vs baseline: 1.1656x; 1.1299x over previous
//
#include <hip/hip_runtime.h>
#include <math.h>

// Disable FP contraction globally: selection thresholds (iou >= 0.5) must be
// bit-exact vs the numpy float32 reference; FMA rewrites would perturb them.
#pragma clang fp contract(off)

#define BN    16      // batch
#define NP    2000    // proposals per batch
#define NG    200     // gt boxes per batch
#define NT    200     // output slots (T)
#define PMAX  66      // int(T * 0.33)
#define EPSF  1e-6f
#define MH    28
#define MW    28
#define HM    56      // input mask H=W
#define NPIX  (HM*HM) // 3136
#define NW    49      // 64-bit words per bit-packed 56x56 plane (3136/64)
#define NGP   256     // padded gt planes per batch (200 used)

#define KA_BLOCKS 128          // 8 blocks/batch * 16 batches
#define KG_BLOCKS (49*4*BN)    // pixel-words * g-words * batch = 3136

// ---------------------------------------------------------------------------
// Kernel F = fused A + G. Block-uniform branch on blockIdx.x; each arm has
// its own __syncthreads (safe: whole block takes one arm).
//
// Arm A (blocks 0..127): per-proposal IOU reductions over GTs.
// Arm G (blocks 128..):  bit-pack ALL 200 gt mask planes per batch.
//   Mask values are exactly {0.0,1.0} (reference: bool -> f32), so a 56x56
//   plane is 49 ulls (392 B). Packing every plane (not just assigned ones)
//   makes the read lane-across-g = perfectly coalesced 256 B bursts over the
//   whole 40 MB input, and removes any dependency on selection results.
//   Double-ballot transpose: per-pixel g-words -> per-g pixel-words.
// ---------------------------------------------------------------------------
__global__ __launch_bounds__(256) void kF(
    const float* __restrict__ proposals, const int* __restrict__ cls_ids,
    const float* __restrict__ boxes, const float* __restrict__ masks,
    int* __restrict__ flag_ws, int* __restrict__ assign_ws,
    unsigned long long* __restrict__ bits)
{
#pragma clang fp contract(off)
  const int tid  = threadIdx.x;
  const int lane = tid & 63;
  const int wv   = tid >> 6;

  __shared__ float4 gbox[NG];
  __shared__ float  garea[NG];
  __shared__ int    gflag[NG];   // 1 non-crowd, 2 crowd, 0 neither
  __shared__ unsigned long long sw[64];  // per-pixel g-words (arm G)

  if (blockIdx.x < KA_BLOCKS) {
    // ---------------- Arm A: IOU / argmax / crowd-max -----------------------
    const int b = blockIdx.x >> 3;          // 8 blocks per batch
    const int bxa = blockIdx.x & 7;

    for (int j = tid; j < NG; j += 256) {
      float4 g = reinterpret_cast<const float4*>(boxes + (size_t)b * NG * 4)[j];
      int c = cls_ids[b * NG + j];
      bool vg = (g.x != 0.f) || (g.y != 0.f) || (g.z != 0.f) || (g.w != 0.f);
      gbox[j]  = g;
      garea[j] = (g.z - g.x) * (g.w - g.y);
      gflag[j] = vg ? (c > 0 ? 1 : (c < 0 ? 2 : 0)) : 0;
    }
    __syncthreads();

    int i = bxa * 256 + tid;
    if (i >= NP) return;

    float4 p = reinterpret_cast<const float4*>(proposals + (size_t)b * NP * 4)[i];
    bool vp = (p.x != 0.f) || (p.y != 0.f) || (p.z != 0.f) || (p.w != 0.f);
    float pa = (p.z - p.x) * (p.w - p.y);

    float best = -3.0e38f;   // first iteration always wins -> argmax-first
    int   bestj = 0;
    float cmax = 0.f;
    for (int j = 0; j < NG; ++j) {
      float4 g = gbox[j];
      float iy = fmaxf(fminf(p.z, g.z) - fmaxf(p.x, g.x), 0.f);
      float ix = fmaxf(fminf(p.w, g.w) - fmaxf(p.y, g.y), 0.f);
      float inter = iy * ix;
      float uni = (pa + garea[j]) - inter;
      float iou = inter / fmaxf(uni, EPSF);
      int fl = gflag[j];
      float v = (fl == 1) ? iou : -1.0f;           // ov_nc
      if (v > best) { best = v; bestj = j; }       // strict > => first max
      if (fl == 2) cmax = fmaxf(cmax, iou);
    }
    bool pos = vp && (best >= 0.5f);
    bool neg = vp && (best < 0.5f) && (cmax < 0.001f);
    flag_ws[b * NP + i]   = pos ? 1 : (neg ? 2 : 0);
    assign_ws[b * NP + i] = bestj;
  } else {
    // ---------------- Arm G: coalesced bit-packing of all planes ------------
    int idx = blockIdx.x - KA_BLOCKS;       // 49 * 4 * BN blocks
    const int pword = idx % 49;             // which 64-pixel word
    idx /= 49;
    const int gw0 = (idx & 3) * 64;         // g-word base (0,64,128,192)
    const int b   = idx >> 2;
    const int p0  = pword * 64;

    const bool gok = (gw0 + lane) < NG;
    const float* mbase = masks + (size_t)b * NPIX * NG + gw0 + lane;
    // read phase: lane = g -> consecutive addresses, fully coalesced
    for (int e = 0; e < 16; ++e) {
      int pl = e * 4 + wv;                  // pixel within this 64-pixel word
      float v = 0.f;
      if (gok) v = mbase[(size_t)(p0 + pl) * NG];
      unsigned long long word = __ballot(v != 0.f);  // bit l = plane gw0+l
      if (lane == 0) sw[pl] = word;
    }
    __syncthreads();

    // bit transpose + write: lane = pixel, each wave emits 16 g-words
    unsigned long long w0 = sw[lane];
    for (int k = 0; k < 16; ++k) {
      int gl = wv * 16 + k;
      unsigned long long word = __ballot((int)((w0 >> gl) & 1ULL));
      if (lane == 0 && (gw0 + gl) < NG)
        bits[(size_t)(b * NGP + gw0 + gl) * NW + pword] = word;
    }
  }
}

// ---------------------------------------------------------------------------
// Kernel B: stable compaction + slot assembly. grid BN, block 256.
// ---------------------------------------------------------------------------
__global__ __launch_bounds__(256) void kB(
    const float* __restrict__ proposals, const int* __restrict__ cls_ids,
    const float* __restrict__ boxes, const int* __restrict__ flag_ws,
    const int* __restrict__ assign_ws, float* __restrict__ out,
    float* __restrict__ mm_ws, int* __restrict__ ma_ws)
{
#pragma clang fp contract(off)
  const int b = blockIdx.x;
  const int tid = threadIdx.x;
  const int lane = tid & 63;
  const int wv = tid >> 6;

  __shared__ unsigned short pos_list[NP];
  __shared__ unsigned short neg_list[NP];
  __shared__ int wcp[4], wcn[4];
  __shared__ int s_pt, s_nt;
  if (tid == 0) { s_pt = 0; s_nt = 0; }
  __syncthreads();

  const int* fb = flag_ws + b * NP;
  for (int base = 0; base < NP; base += 256) {
    int i = base + tid;
    int f = (i < NP) ? fb[i] : 0;
    bool isp = (f == 1), isn = (f == 2);
    unsigned long long bp = __ballot(isp);
    unsigned long long bn = __ballot(isn);
    __syncthreads();
    if (lane == 0) { wcp[wv] = __popcll(bp); wcn[wv] = __popcll(bn); }
    __syncthreads();
    int prep = __popcll(bp & ((1ull << lane) - 1ull));
    int pren = __popcll(bn & ((1ull << lane) - 1ull));
    int bpp = 0, bnn = 0, tp = 0, tn = 0;
    for (int w = 0; w < 4; ++w) {
      if (w < wv) { bpp += wcp[w]; bnn += wcn[w]; }
      tp += wcp[w]; tn += wcn[w];
    }
    int pt = s_pt, nt = s_nt;
    if (isp) pos_list[pt + bpp + prep] = (unsigned short)i;
    if (isn) neg_list[nt + bnn + pren] = (unsigned short)i;
    __syncthreads();
    if (tid == 0) { s_pt = pt + tp; s_nt = nt + tn; }
  }
  __syncthreads();

  int pos_total = s_pt, neg_total = s_nt;
  int pos_count = min(pos_total, PMAX);
  int neg_needed = (int)floorf((float)pos_count / 0.33f) - pos_count;
  int neg_count = min(min(neg_needed, neg_total), NT - pos_count);

  if (tid < NT) {
    bool ispos = tid < pos_count;
    bool isneg = (!ispos) && (tid < pos_count + neg_count);
    float r0 = 0.f, r1 = 0.f, r2 = 0.f, r3 = 0.f;
    float d0 = 0.f, d1 = 0.f, d2 = 0.f, d3 = 0.f;
    float m0 = 0.f, m1 = 0.f, m2 = 0.f, m3 = 0.f;
    float clsf = 0.f;
    int ma = -1;
    if (ispos || isneg) {
      int i = ispos ? (int)pos_list[tid] : (int)neg_list[tid - pos_count];
      float4 p = reinterpret_cast<const float4*>(proposals + (size_t)b * NP * 4)[i];
      r0 = p.x; r1 = p.y; r2 = p.z; r3 = p.w;
      if (ispos) {
        int a = assign_ws[b * NP + i];
        ma = a;
        float4 g = reinterpret_cast<const float4*>(boxes + (size_t)b * NG * 4)[a];
        float h  = fmaxf(r2 - r0, EPSF);
        float w  = fmaxf(r3 - r1, EPSF);
        float cy = r0 + 0.5f * h;
        float cx = r1 + 0.5f * w;
        float gh = fmaxf(g.z - g.x, EPSF);
        float gw = fmaxf(g.w - g.y, EPSF);
        float gcy = g.x + 0.5f * gh;
        float gcx = g.y + 0.5f * gw;
        d0 = ((gcy - cy) / h) / 0.1f;
        d1 = ((gcx - cx) / w) / 0.1f;
        d2 = logf(gh / h) / 0.2f;
        d3 = logf(gw / w) / 0.2f;
        m0 = (r0 - g.x) / gh;
        m1 = (r1 - g.y) / gw;
        m2 = (r2 - g.x) / gh;
        m3 = (r3 - g.y) / gw;
        clsf = (float)cls_ids[b * NG + a];
      }
    }
    int s = b * NT + tid;
    float* rois = out;                         // [BN*NT*4]
    float* cls  = out + BN * NT * 4;           // [BN*NT]
    float* dlt  = out + BN * NT * 4 + BN * NT; // [BN*NT*4]
    rois[s * 4 + 0] = r0; rois[s * 4 + 1] = r1;
    rois[s * 4 + 2] = r2; rois[s * 4 + 3] = r3;
    cls[s] = clsf;
    dlt[s * 4 + 0] = d0; dlt[s * 4 + 1] = d1;
    dlt[s * 4 + 2] = d2; dlt[s * 4 + 3] = d3;
    mm_ws[s * 4 + 0] = m0; mm_ws[s * 4 + 1] = m1;
    mm_ws[s * 4 + 2] = m2; mm_ws[s * 4 + 3] = m3;
    ma_ws[s] = ma;
  }
}

// ---------------------------------------------------------------------------
// Kernel C: bilinear crop-resize from bit-packed planes. grid BN*NT, block 256.
// Plane = 49 ulls in LDS, indexed by the slot's ASSIGNED GT id. Reconstructed
// values are exactly 0.0/1.0 so the f32 arithmetic (and rintf ties) is
// bit-identical to the float-staged version. Each active thread computes 4
// consecutive pixels (28 % 4 == 0 -> same row), stores float4.
// ---------------------------------------------------------------------------
__global__ __launch_bounds__(256) void kC(
    const unsigned long long* __restrict__ bits, const float* __restrict__ mm_ws,
    const int* __restrict__ ma_ws, float* __restrict__ out)
{
#pragma clang fp contract(off)
  const int s = blockIdx.x;                    // b*NT + t
  float4* om = reinterpret_cast<float4*>(
      out + (size_t)(BN * NT * 9) + (size_t)s * (MH * MW));
  const int q = threadIdx.x;                   // float4 index, 196 active
  const int a = ma_ws[s];                      // block-uniform
  if (a < 0) {
    if (q < (MH * MW) / 4) om[q] = make_float4(0.f, 0.f, 0.f, 0.f);
    return;
  }

  __shared__ unsigned long long pb[NW];
  const int b = s / NT;
  if (q < NW) pb[q] = bits[(size_t)(b * NGP + a) * NW + q];
  __syncthreads();
  if (q >= (MH * MW) / 4) return;

  float y1 = mm_ws[s * 4 + 0], x1 = mm_ws[s * 4 + 1];
  float y2 = mm_ws[s * 4 + 2], x2 = mm_ws[s * 4 + 3];
  float sy = (y2 - y1) * 55.0f / 27.0f;        // reference order
  float sx = (x2 - x1) * 55.0f / 27.0f;

  int px0 = q * 4;
  int my  = px0 / MW;                          // same row for all 4
  float ys = y1 * 55.0f + (float)my * sy;
  float y0f = floorf(ys);
  float wy  = ys - y0f;
  int y0i = (int)fminf(fmaxf(y0f, 0.f), 55.f);
  int y1i = (int)fminf(fmaxf(y0f + 1.0f, 0.f), 55.f);
  bool oky = (ys >= 0.f) && (ys <= 55.f);
  const int r0b = y0i * HM;
  const int r1b = y1i * HM;

  float res[4];
  for (int k = 0; k < 4; ++k) {
    int mx = (px0 + k) - my * MW;
    float xs = x1 * 55.0f + (float)mx * sx;
    float x0f = floorf(xs);
    float wx  = xs - x0f;
    int x0i = (int)fminf(fmaxf(x0f, 0.f), 55.f);
    int x1i = (int)fminf(fmaxf(x0f + 1.0f, 0.f), 55.f);
    int p00 = r0b + x0i, p01 = r0b + x1i;
    int p10 = r1b + x0i, p11 = r1b + x1i;
    float v00 = (float)((pb[p00 >> 6] >> (p00 & 63)) & 1ULL);
    float v01 = (float)((pb[p01 >> 6] >> (p01 & 63)) & 1ULL);
    float v10 = (float)((pb[p10 >> 6] >> (p10 & 63)) & 1ULL);
    float v11 = (float)((pb[p11 >> 6] >> (p11 & 63)) & 1ULL);
    float val = (v00 * (1.f - wx) + v01 * wx) * (1.f - wy)
              + (v10 * (1.f - wx) + v11 * wx) * wy;
    bool ok = oky && (xs >= 0.f) && (xs <= 55.f);
    res[k] = ok ? rintf(val) : 0.f;            // rintf = ties-even = np.round
  }
  om[q] = make_float4(res[0], res[1], res[2], res[3]);
}

// ---------------------------------------------------------------------------
extern "C" void kernel_launch(void* const* d_in, const int* in_sizes, int n_in,
                              void* d_out, int out_size, void* d_ws, size_t ws_size,
                              hipStream_t stream)
{
  const float* proposals = (const float*)d_in[0];   // (16,2000,4)
  const int*   cls_ids   = (const int*)d_in[1];     // (16,200)
  const float* boxes     = (const float*)d_in[2];   // (16,200,4)
  const float* masks     = (const float*)d_in[3];   // (16,56,56,200)
  float* out = (float*)d_out;

  char* ws = (char*)d_ws;
  int*   flag_ws   = (int*)ws;    ws += (size_t)BN * NP * sizeof(int);
  int*   assign_ws = (int*)ws;    ws += (size_t)BN * NP * sizeof(int);
  float* mm_ws     = (float*)ws;  ws += (size_t)BN * NT * 4 * sizeof(float);
  int*   ma_ws     = (int*)ws;    ws += (size_t)BN * NT * sizeof(int);
  unsigned long long* bits_ws = (unsigned long long*)ws; // BN*NGP*49 ulls = 1.6 MB

  kF<<<KA_BLOCKS + KG_BLOCKS, 256, 0, stream>>>(
      proposals, cls_ids, boxes, masks, flag_ws, assign_ws, bits_ws);
  kB<<<BN, 256, 0, stream>>>(proposals, cls_ids, boxes, flag_ws, assign_ws,
                             out, mm_ws, ma_ws);
  kC<<<BN * NT, 256, 0, stream>>>(bits_ws, mm_ws, ma_ws, out);
}